// Round 1
// baseline (939.102 us; speedup 1.0000x reference)
//
#include <hip/hip_runtime.h>
#include <hip/hip_bf16.h>
#include <cstdint>
#include <cstddef>

// Problem constants (NeuTraLAD): B=8192, D=512, H=1024, K=11 views.
#define NB 8192
#define ND 512
#define NH 1024
#define NK 11

typedef __bf16 bf16x8 __attribute__((ext_vector_type(8)));
typedef float f32x4 __attribute__((ext_vector_type(4)));

// ---------------------------------------------------------------------------
// Convert f32 -> bf16 elementwise
// ---------------------------------------------------------------------------
__global__ void cvt_f32_bf16(const float* __restrict__ in,
                             __hip_bfloat16* __restrict__ out, int n) {
  int i = blockIdx.x * blockDim.x + threadIdx.x;
  if (i < n) out[i] = __float2bfloat16(in[i]);
}

// ---------------------------------------------------------------------------
// ONE preamble launch: all four weight transposes f32 [R,C] -> bf16 [C,R].
// z 0..10 = Wt1 slices, 11..21 = Wt2 slices, 22 = We1, 23 = We2.
// ---------------------------------------------------------------------------
__global__ void transpose_all(const float* __restrict__ Wt1,
                              const float* __restrict__ Wt2,
                              const float* __restrict__ We1,
                              const float* __restrict__ We2,
                              __hip_bfloat16* __restrict__ Wt1t,
                              __hip_bfloat16* __restrict__ Wt2t,
                              __hip_bfloat16* __restrict__ We1t,
                              __hip_bfloat16* __restrict__ We2t) {
  __shared__ float tile[32][33];
  const int z = blockIdx.z;
  int R, C;
  const float* inb;
  __hip_bfloat16* outb;
  if (z < NK) {
    R = ND; C = NH;
    inb = Wt1 + (size_t)z * ND * NH;
    outb = Wt1t + (size_t)z * ND * NH;
  } else if (z < 2 * NK) {
    R = NH; C = ND;
    inb = Wt2 + (size_t)(z - NK) * NH * ND;
    outb = Wt2t + (size_t)(z - NK) * NH * ND;
  } else if (z == 2 * NK) {
    R = ND; C = NH;
    inb = We1; outb = We1t;
  } else {
    R = NH; C = NH;
    inb = We2; outb = We2t;
  }
  int cx = blockIdx.x * 32 + threadIdx.x;
  int ry = blockIdx.y * 32;
  if (blockIdx.x * 32 >= C || ry >= R) return;  // uniform early-out
  for (int j = threadIdx.y; j < 32; j += 8)
    tile[j][threadIdx.x] = inb[(size_t)(ry + j) * C + cx];
  __syncthreads();
  int ox = ry + threadIdx.x;
  int oy = blockIdx.x * 32;
  for (int j = threadIdx.y; j < 32; j += 8)
    outb[(size_t)(oy + j) * R + ox] = __float2bfloat16(tile[threadIdx.x][j]);
}

__device__ __forceinline__ float fast_tanh(float x) {
  float e = __expf(2.0f * x);
  return 1.0f - 2.0f / (e + 1.0f);
}

// ---------------------------------------------------------------------------
// LEGACY MFMA GEMM (NT, m97-structure): kept ONLY for G2 (N=512 -> 352-block
// tail makes the 1-block/CU 8-phase kernel a poor fit; also serves as the
// in-run control for the 8-phase experiment). Unchanged from R11 config.
// ---------------------------------------------------------------------------
template <int EPI, int BK, int TM, int TN>
__global__ __launch_bounds__((TM / 64) * (TN / 64) * 64) void gemm_bt(
    const __hip_bfloat16* __restrict__ A, long sAz, int lda,
    const __hip_bfloat16* __restrict__ Bt, long sBz, int ldb,
    const float* __restrict__ bias, long sBiasZ,
    __hip_bfloat16* __restrict__ C, long sCz, int ldc, int Kd) {
  __shared__ __align__(16) __hip_bfloat16 As[TM * BK];
  __shared__ __align__(16) __hip_bfloat16 Bs[TN * BK];

  const int z = blockIdx.z;
  const __hip_bfloat16* Ab = A + (size_t)z * sAz;
  const __hip_bfloat16* Bb = Bt + (size_t)z * sBz;
  const float* biasb = bias + (size_t)z * sBiasZ;
  __hip_bfloat16* Cb = C + (size_t)z * sCz;

  const int bm = blockIdx.x, bn = blockIdx.y;  // x = row panel (XCD affinity)
  const int t = threadIdx.x;
  constexpr int NWN = TN / 64;
  constexpr int T = (TM / 64) * NWN * 64;  // threads
  const int lane = t & 63, w = t >> 6;
  const int wm = w / NWN, wn = w % NWN;
  const int r = lane & 15, q = lane >> 4;

  f32x4 acc[4][4] = {};

  auto chunk_row = [&](int c) {
    return (BK == 32) ? (c >> 2) : (c >> 3);
  };
  auto chunk_gofs = [&](int c, int row) {
    return (BK == 32) ? ((((c & 3) ^ ((row >> 1) & 3)) * 8))
                      : ((((c & 7) ^ (row & 7)) * 8));
  };
  constexpr int CPTA = TM * BK / 8 / T;  // A chunks per thread
  constexpr int CPTB = TN * BK / 8 / T;  // B chunks per thread
  const size_t rowA = (size_t)bm * TM, rowB = (size_t)bn * TN;

  for (int k0 = 0; k0 < Kd; k0 += BK) {
#pragma unroll
    for (int m = 0; m < CPTA; ++m) {
      int c = t + m * T;
      int rw = chunk_row(c);
      __builtin_amdgcn_global_load_lds(
          (const __attribute__((address_space(1))) void*)(Ab + (rowA + rw) * lda + k0 + chunk_gofs(c, rw)),
          (__attribute__((address_space(3))) void*)(As + c * 8), 16, 0, 0);
    }
#pragma unroll
    for (int m = 0; m < CPTB; ++m) {
      int c = t + m * T;
      int rw = chunk_row(c);
      __builtin_amdgcn_global_load_lds(
          (const __attribute__((address_space(1))) void*)(Bb + (rowB + rw) * ldb + k0 + chunk_gofs(c, rw)),
          (__attribute__((address_space(3))) void*)(Bs + c * 8), 16, 0, 0);
    }
    __syncthreads();

#pragma unroll
    for (int ks = 0; ks < BK / 32; ++ks) {
      bf16x8 af[4], bfr[4];
#pragma unroll
      for (int mt = 0; mt < 4; ++mt) {
        int tr = wm * 64 + mt * 16 + r;
        int sl;
        if constexpr (BK == 32) sl = q ^ ((tr >> 1) & 3);
        else sl = (ks * 4 + q) ^ (tr & 7);
        af[mt] = *(const bf16x8*)&As[tr * BK + sl * 8];
      }
#pragma unroll
      for (int nt = 0; nt < 4; ++nt) {
        int tr = wn * 64 + nt * 16 + r;
        int sl;
        if constexpr (BK == 32) sl = q ^ ((tr >> 1) & 3);
        else sl = (ks * 4 + q) ^ (tr & 7);
        bfr[nt] = *(const bf16x8*)&Bs[tr * BK + sl * 8];
      }
#pragma unroll
      for (int mt = 0; mt < 4; ++mt)
#pragma unroll
        for (int nt = 0; nt < 4; ++nt)
          acc[mt][nt] = __builtin_amdgcn_mfma_f32_16x16x32_bf16(
              bfr[nt], af[mt], acc[mt][nt], 0, 0, 0);
    }
    __syncthreads();
  }

  const int colg0 = bn * TN + wn * 64;
  const int rowg0 = bm * TM + wm * 64;
#pragma unroll
  for (int mt = 0; mt < 4; ++mt) {
    int row = rowg0 + mt * 16 + r;
#pragma unroll
    for (int nt = 0; nt < 4; ++nt) {
      int col = colg0 + nt * 16 + q * 4;
      const f32x4 bv = *(const f32x4*)&biasb[col];
      union {
        __hip_bfloat16 h[4];
        uint2 u;
      } pk;
#pragma unroll
      for (int j = 0; j < 4; ++j) {
        float v = acc[mt][nt][j] + bv[j];
        if (EPI == 1) v = fast_tanh(v);
        if (EPI == 2) v = fmaxf(v, 0.0f);
        pk.h[j] = __float2bfloat16(v);
      }
      *(uint2*)&Cb[(size_t)row * ldc + col] = pk.u;
    }
  }
}

// ---------------------------------------------------------------------------
// R14: 8-PHASE 256x256 GEMM (T3+T4 counted-vmcnt + T5 setprio; guide §5
// template, m201 geometry). 8 waves (2Mx4N), BK=64, 128 KiB LDS (2 dbuf x
// 2 halves x 128x64 x {A,B}). Per-wave output 128x64 = 8x4 f32x4 acc.
// Requires: M%256==0, N%256==0, Kd%128==0 (NT=Kd/64 even, >=4).
//
// Schedule per K-tile t (buf = t&1), 4 phases, 2 barriers each:
//   ph1: read af[0..3][ks], bfr[n0,n1][ks]; stage B1(t+1)->Bs[buf^1][1]
//   ph2: read af[4..7][ks]
//   ph3: read bfr[n2,n3][ks]; stage A0(t+2)->As[buf][0]
//   ph4: stage A1(t+2)->As[buf][1], B0(t+2)->Bs[buf][0]; vmcnt(6)
// Every phase: reads+stage; s_barrier; lgkmcnt(0)+sched_barrier(0) [rule
// #18]; setprio(1); 16 MFMA; setprio(0); s_barrier.
// WAR safety: every LDS region is overwritten only AFTER the barrier that
// follows the last read of it (A0 read ph1/ph2, staged ph3; A1 read
// ph1/ph2, staged ph4; B0 read ph1/ph3, staged ph4; B1(t+1) goes to the
// other buffer). RAW safety: vmcnt(6) at ph4 completes exactly the 4
// half-tiles of t+1 (steady state 14 outstanding -> keep newest 6 =
// A0,A1,B0 of t+2), then barrier; tile t+1's reads follow it.
// vmcnt(0) NEVER in the main loop (T4 — that drain is the m97 ~33% cap).
// Swizzle identical to legacy (SQ_LDS_BANK_CONFLICT was 0): chunk c of a
// half: row=c>>3, gofs=((c&7)^(row&7))*8; read sl=(ks*4+q)^(r&7).
// ---------------------------------------------------------------------------
#define BAR8() asm volatile("s_barrier" ::: "memory")
#define LGKM0_8()                                      \
  do {                                                 \
    asm volatile("s_waitcnt lgkmcnt(0)" ::: "memory"); \
    __builtin_amdgcn_sched_barrier(0);                 \
  } while (0)

template <int EPI>
__global__ __launch_bounds__(512, 2) void gemm8p(
    const __hip_bfloat16* __restrict__ A, long sAz, int lda,
    const __hip_bfloat16* __restrict__ Bt, long sBz, int ldb,
    const float* __restrict__ bias, long sBiasZ,
    __hip_bfloat16* __restrict__ C, long sCz, int ldc, int Kd) {
  __shared__ __align__(16) __hip_bfloat16 As[2][2][128 * 64];  // [buf][half]
  __shared__ __align__(16) __hip_bfloat16 Bs[2][2][128 * 64];

  const int z = blockIdx.z;
  const __hip_bfloat16* Ab = A + (size_t)z * sAz;
  const __hip_bfloat16* Bb = Bt + (size_t)z * sBz;
  const float* biasb = bias + (size_t)z * sBiasZ;
  __hip_bfloat16* Cb = C + (size_t)z * sCz;

  const int bm = blockIdx.x, bn = blockIdx.y;  // x = row panel (XCD affinity)
  const int t = threadIdx.x;
  const int lane = t & 63, w = t >> 6;  // 8 waves
  const int wm = w >> 2, wn = w & 3;    // 2 x 4
  const int r = lane & 15, q = lane >> 4;
  const int rx = r & 7;
  const int ao0 = (q ^ rx) * 8;        // k-slice 0 LDS chunk offset
  const int ao1 = ((4 + q) ^ rx) * 8;  // k-slice 1
  const int brl = (wn & 1) * 64;       // B row-in-half base

  const size_t rowA = (size_t)bm * 256;
  const size_t rowB = (size_t)bn * 256;

  f32x4 acc[8][4] = {};

  // Stage one 128x64 half-tile: 1024 16B chunks, 2 per thread, linear LDS
  // dest (global_load_lds requirement) with pre-swizzled global source.
  auto stage = [&](const __hip_bfloat16* gb, int ldg, size_t rbase,
                   __hip_bfloat16* dst, int kt) {
#pragma unroll
    for (int i = 0; i < 2; ++i) {
      int c = t + i * 512;
      int rw = c >> 3;
      int go = ((c & 7) ^ (rw & 7)) * 8;
      __builtin_amdgcn_global_load_lds(
          (const __attribute__((address_space(1))) void*)(
              gb + (rbase + rw) * (size_t)ldg + kt * 64 + go),
          (__attribute__((address_space(3))) void*)(dst + c * 8), 16, 0, 0);
    }
  };

  auto do_tile = [&](int buf, int ktB1, int ktN, int nstage, int vmN) {
    const __hip_bfloat16* Ap = &As[buf][wm][0];
    const __hip_bfloat16* Bp = &Bs[buf][wn >> 1][0];
    bf16x8 af[8][2];
    bf16x8 bfr[2][2];

    // ---- phase 1: quadrant (m0-3 x n0-1)
#pragma unroll
    for (int mt = 0; mt < 4; ++mt) {
      af[mt][0] = *(const bf16x8*)&Ap[(mt * 16 + r) * 64 + ao0];
      af[mt][1] = *(const bf16x8*)&Ap[(mt * 16 + r) * 64 + ao1];
    }
#pragma unroll
    for (int nt = 0; nt < 2; ++nt) {
      bfr[nt][0] = *(const bf16x8*)&Bp[(brl + nt * 16 + r) * 64 + ao0];
      bfr[nt][1] = *(const bf16x8*)&Bp[(brl + nt * 16 + r) * 64 + ao1];
    }
    if (nstage >= 1) stage(Bb, ldb, rowB + 128, &Bs[buf ^ 1][1][0], ktB1);
    BAR8();
    LGKM0_8();
    __builtin_amdgcn_s_setprio(1);
#pragma unroll
    for (int mt = 0; mt < 4; ++mt)
#pragma unroll
      for (int nt = 0; nt < 2; ++nt) {
        acc[mt][nt] = __builtin_amdgcn_mfma_f32_16x16x32_bf16(
            bfr[nt][0], af[mt][0], acc[mt][nt], 0, 0, 0);
        acc[mt][nt] = __builtin_amdgcn_mfma_f32_16x16x32_bf16(
            bfr[nt][1], af[mt][1], acc[mt][nt], 0, 0, 0);
      }
    __builtin_amdgcn_s_setprio(0);
    BAR8();

    // ---- phase 2: quadrant (m4-7 x n0-1), reuse bfr
#pragma unroll
    for (int mt = 4; mt < 8; ++mt) {
      af[mt][0] = *(const bf16x8*)&Ap[(mt * 16 + r) * 64 + ao0];
      af[mt][1] = *(const bf16x8*)&Ap[(mt * 16 + r) * 64 + ao1];
    }
    BAR8();
    LGKM0_8();
    __builtin_amdgcn_s_setprio(1);
#pragma unroll
    for (int mt = 4; mt < 8; ++mt)
#pragma unroll
      for (int nt = 0; nt < 2; ++nt) {
        acc[mt][nt] = __builtin_amdgcn_mfma_f32_16x16x32_bf16(
            bfr[nt][0], af[mt][0], acc[mt][nt], 0, 0, 0);
        acc[mt][nt] = __builtin_amdgcn_mfma_f32_16x16x32_bf16(
            bfr[nt][1], af[mt][1], acc[mt][nt], 0, 0, 0);
      }
    __builtin_amdgcn_s_setprio(0);
    BAR8();

    // ---- phase 3: quadrant (m0-3 x n2-3); A0(t+2) reads finished ph2
#pragma unroll
    for (int nt = 0; nt < 2; ++nt) {
      bfr[nt][0] = *(const bf16x8*)&Bp[(brl + (nt + 2) * 16 + r) * 64 + ao0];
      bfr[nt][1] = *(const bf16x8*)&Bp[(brl + (nt + 2) * 16 + r) * 64 + ao1];
    }
    if (nstage >= 4) stage(Ab, lda, rowA + 0, &As[buf][0][0], ktN);
    BAR8();
    LGKM0_8();
    __builtin_amdgcn_s_setprio(1);
#pragma unroll
    for (int mt = 0; mt < 4; ++mt)
#pragma unroll
      for (int nt = 0; nt < 2; ++nt) {
        acc[mt][nt + 2] = __builtin_amdgcn_mfma_f32_16x16x32_bf16(
            bfr[nt][0], af[mt][0], acc[mt][nt + 2], 0, 0, 0);
        acc[mt][nt + 2] = __builtin_amdgcn_mfma_f32_16x16x32_bf16(
            bfr[nt][1], af[mt][1], acc[mt][nt + 2], 0, 0, 0);
      }
    __builtin_amdgcn_s_setprio(0);
    BAR8();

    // ---- phase 4: quadrant (m4-7 x n2-3); A1/B0 reads finished ph2/ph3
    if (nstage >= 4) {
      stage(Ab, lda, rowA + 128, &As[buf][1][0], ktN);
      stage(Bb, ldb, rowB + 0, &Bs[buf][0][0], ktN);
    }
    if (vmN == 6) {
      asm volatile("s_waitcnt vmcnt(6)" ::: "memory");
      __builtin_amdgcn_sched_barrier(0);
    } else if (vmN == 0) {
      asm volatile("s_waitcnt vmcnt(0)" ::: "memory");
      __builtin_amdgcn_sched_barrier(0);
    }
    BAR8();
    __builtin_amdgcn_s_setprio(1);
#pragma unroll
    for (int mt = 4; mt < 8; ++mt)
#pragma unroll
      for (int nt = 0; nt < 2; ++nt) {
        acc[mt][nt + 2] = __builtin_amdgcn_mfma_f32_16x16x32_bf16(
            bfr[nt][0], af[mt][0], acc[mt][nt + 2], 0, 0, 0);
        acc[mt][nt + 2] = __builtin_amdgcn_mfma_f32_16x16x32_bf16(
            bfr[nt][1], af[mt][1], acc[mt][nt + 2], 0, 0, 0);
      }
    __builtin_amdgcn_s_setprio(0);
    BAR8();
  };

  // Prologue: tile0 fully + tile1 {A0,A1,B0} (7 half-tiles, 14 loads);
  // vmcnt(6) completes tile0, leaves tile1's 3 halves in flight.
  stage(Ab, lda, rowA + 0, &As[0][0][0], 0);
  stage(Ab, lda, rowA + 128, &As[0][1][0], 0);
  stage(Bb, ldb, rowB + 0, &Bs[0][0][0], 0);
  stage(Bb, ldb, rowB + 128, &Bs[0][1][0], 0);
  stage(Ab, lda, rowA + 0, &As[1][0][0], 1);
  stage(Ab, lda, rowA + 128, &As[1][1][0], 1);
  stage(Bb, ldb, rowB + 0, &Bs[1][0][0], 1);
  asm volatile("s_waitcnt vmcnt(6)" ::: "memory");
  __builtin_amdgcn_sched_barrier(0);
  BAR8();

  const int NT = Kd >> 6;  // even, >= 4 for all our shapes (8 or 16)
  for (int kt = 0; kt + 4 <= NT; kt += 2) {
    do_tile(0, kt + 1, kt + 2, 4, 6);
    do_tile(1, kt + 2, kt + 3, 4, 6);
  }
  // Epilogue pair: tile NT-2 stages only B1(NT-1) then drains; NT-1 computes.
  do_tile(0, NT - 1, 0, 1, 0);
  do_tile(1, 0, 0, 0, -1);

  // C-write (operand-swapped mapping, verified in legacy kernel):
  // row = rowg0 + mt*16 + r, cols nt*16 + q*4 + j -> 8 B packed stores.
  const int colg0 = bn * 256 + wn * 64;
  const int rowg0 = bm * 256 + wm * 128;
#pragma unroll
  for (int mt = 0; mt < 8; ++mt) {
    int row = rowg0 + mt * 16 + r;
#pragma unroll
    for (int nt = 0; nt < 4; ++nt) {
      int col = colg0 + nt * 16 + q * 4;
      const f32x4 bv = *(const f32x4*)&biasb[col];
      union {
        __hip_bfloat16 h[4];
        uint2 u;
      } pk;
#pragma unroll
      for (int j = 0; j < 4; ++j) {
        float v = acc[mt][nt][j] + bv[j];
        if (EPI == 1) v = fast_tanh(v);
        if (EPI == 2) v = fmaxf(v, 0.0f);
        pk.h[j] = __float2bfloat16(v);
      }
      *(uint2*)&Cb[(size_t)row * ldc + col] = pk.u;
    }
  }
}

// ---------------------------------------------------------------------------
// Final: zc laid [Bc][12][NH]; 2 waves per b (half-H each), partial Grams
// summed in LDS. Block = 256 thr = 2 b's.
// ---------------------------------------------------------------------------
__global__ __launch_bounds__(256) void final_gram(
    const __hip_bfloat16* __restrict__ zc, float* __restrict__ out, int Bc) {
  __shared__ float Gs[2][2][16][16];
  const int t = threadIdx.x;
  const int w = t >> 6, lane = t & 63;
  const int bi = w >> 1;
  const int hh = w & 1;
  const int b = blockIdx.x * 2 + bi;
  const int r = lane & 15;
  const int q = lane >> 4;

  const int rs = r < 12 ? r : 11;
  const __hip_bfloat16* base =
      zc + ((size_t)b * 12 + rs) * NH + hh * (NH / 2) + q * 8;

  f32x4 acc = {};
#pragma unroll
  for (int k0 = 0; k0 < NH / 2; k0 += 32) {
    bf16x8 a = {};
    if (r < 12) a = *(const bf16x8*)(base + k0);
    acc = __builtin_amdgcn_mfma_f32_16x16x32_bf16(a, a, acc, 0, 0, 0);
  }

#pragma unroll
  for (int j = 0; j < 4; ++j) Gs[bi][hh][q * 4 + j][r] = acc[j];
  __syncthreads();

  if (hh == 0) {
    float term = 0.0f;
    if (lane >= 1 && lane < 12) {
      const float(*G0)[16] = Gs[bi][0];
      const float(*G1)[16] = Gs[bi][1];
      float nrm[12];
#pragma unroll
      for (int i = 0; i < 12; ++i)
        nrm[i] = fmaxf(sqrtf(G0[i][i] + G1[i][i]), 1e-8f);
      const int k = lane;
      float pos = __expf((G0[0][k] + G1[0][k]) / (nrm[0] * nrm[k]));
      float neg = 0.0f;
#pragma unroll
      for (int l = 1; l < 12; ++l)
        if (l != k) neg += __expf((G0[k][l] + G1[k][l]) / (nrm[k] * nrm[l]));
      term = __logf(pos / (pos + neg));
    }
#pragma unroll
    for (int m = 1; m < 16; m <<= 1) term += __shfl_xor(term, m);
    if (lane == 0) out[b] = -term;
  }
}

// ---------------------------------------------------------------------------
extern "C" void kernel_launch(void* const* d_in, const int* in_sizes, int n_in,
                              void* d_out, int out_size, void* d_ws,
                              size_t ws_size, hipStream_t stream) {
  const float* x = (const float*)d_in[0];    // [B,D]
  const float* Wt1 = (const float*)d_in[1];  // [K,D,H]
  const float* bt1 = (const float*)d_in[2];  // [K,H]
  const float* Wt2 = (const float*)d_in[3];  // [K,H,D]
  const float* bt2 = (const float*)d_in[4];  // [K,D]
  const float* We1 = (const float*)d_in[5];  // [D,H]
  const float* be1 = (const float*)d_in[6];  // [H]
  const float* We2 = (const float*)d_in[7];  // [H,H]
  const float* be2 = (const float*)d_in[8];  // [H]
  float* out = (float*)d_out;                // [B]

  char* ws = (char*)d_ws;
  size_t off = 0;
  auto alloc = [&](size_t bytes) {
    void* p = ws + off;
    off += (bytes + 255) & ~(size_t)255;
    return p;
  };

  // Persistent bf16 weight transposes (~26 MB)
  __hip_bfloat16* Wt1t = (__hip_bfloat16*)alloc((size_t)NK * NH * ND * 2);  // [K,H,D]
  __hip_bfloat16* Wt2t = (__hip_bfloat16*)alloc((size_t)NK * ND * NH * 2);  // [K,D,H]
  __hip_bfloat16* We1t = (__hip_bfloat16*)alloc((size_t)NH * ND * 2);       // [H,D]
  __hip_bfloat16* We2t = (__hip_bfloat16*)alloc((size_t)NH * NH * 2);       // [H,H]
  const size_t wbytes = off;

  // Pick largest batch chunk Bc (ws in [228,253) MB -> Bc=4096).
  // zc ALIASES txc's region (txc dead after G3).
  int Bc = NB;
  while (Bc > 256) {
    size_t need = wbytes + 2 * ((size_t)12 * Bc * NH * 2) + 4096;
    if (need <= ws_size) break;
    Bc >>= 1;
  }
  __hip_bfloat16* region0 = (__hip_bfloat16*)alloc((size_t)12 * Bc * NH * 2);
  __hip_bfloat16* h1 = (__hip_bfloat16*)alloc((size_t)12 * Bc * NH * 2);
  __hip_bfloat16* txc = region0;  // [12, Bc, ND] during G1..G3
  __hip_bfloat16* zc = region0;   // [Bc, 12, NH] during G4..final

  // One-time: all weight transposes in ONE launch
  transpose_all<<<dim3(NH / 32, NH / 32, 2 * NK + 2), dim3(32, 8), 0,
                  stream>>>(Wt1, Wt2, We1, We2, Wt1t, Wt2t, We1t, We2t);

  for (int cs = 0; cs < NB; cs += Bc) {
    // 1) x chunk -> bf16 (slice 0 of txc)
    cvt_f32_bf16<<<(Bc * ND) / 256, 256, 0, stream>>>(
        x + (size_t)cs * ND, txc, Bc * ND);
    // 2) G1: hx_k = tanh(x @ Wt1[k] + bt1) -> h1 slices 0..10
    //    8-phase kernel: grid 16x4x11 = 704 blocks @ 1 blk/CU.
    gemm8p<1><<<dim3(Bc / 256, NH / 256, NK), 512, 0, stream>>>(
        txc, 0L, ND, Wt1t, (long)NH * ND, ND, bt1, (long)NH, h1,
        (long)Bc * NH, NH, ND);
    // 3) G2: tx_k = hx_k @ Wt2[k] + bt2 -> txc slices 1..11
    //    LEGACY config (N=512 tail fits badly at 1 blk/CU; in-run control).
    gemm_bt<3, 64, 256, 128><<<dim3(Bc / 256, ND / 128, NK), 512, 0,
                               stream>>>(
        h1, (long)Bc * NH, NH, Wt2t, (long)ND * NH, NH, bt2, (long)ND,
        txc + (size_t)Bc * ND, (long)Bc * ND, ND, NH);
    // 4) G3: e1_s = relu(tx_s @ We1 + be1) -> h1 slices 0..11
    //    8-phase: grid 16x4x12 = 768 = exactly 3 full CU-rounds.
    gemm8p<2><<<dim3(Bc / 256, NH / 256, 12), 512, 0, stream>>>(
        txc, (long)Bc * ND, ND, We1t, 0L, ND, be1, 0L, h1, (long)Bc * NH,
        NH, ND);
    // 5) G4: z_s -> zc [b][s][h] (sCz=NH, ldc=12NH; Kd=1024)
    //    8-phase: grid 768 = 3 full rounds.
    gemm8p<3><<<dim3(Bc / 256, NH / 256, 12), 512, 0, stream>>>(
        h1, (long)Bc * NH, NH, We2t, 0L, NH, be2, 0L, zc, (long)NH,
        12 * NH, NH);
    // 6) final score
    final_gram<<<Bc / 2, 256, 0, stream>>>(zc, out + cs, Bc);
  }
}

// Round 2
// 876.559 us; speedup vs baseline: 1.0714x; 1.0714x over previous
//
#include <hip/hip_runtime.h>
#include <hip/hip_bf16.h>
#include <cstdint>
#include <cstddef>

// Problem constants (NeuTraLAD): B=8192, D=512, H=1024, K=11 views.
#define NB 8192
#define ND 512
#define NH 1024
#define NK 11

typedef __bf16 bf16x8 __attribute__((ext_vector_type(8)));
typedef float f32x4 __attribute__((ext_vector_type(4)));
typedef float f32x16 __attribute__((ext_vector_type(16)));

// ---------------------------------------------------------------------------
// Convert f32 -> bf16 elementwise
// ---------------------------------------------------------------------------
__global__ void cvt_f32_bf16(const float* __restrict__ in,
                             __hip_bfloat16* __restrict__ out, int n) {
  int i = blockIdx.x * blockDim.x + threadIdx.x;
  if (i < n) out[i] = __float2bfloat16(in[i]);
}

// ---------------------------------------------------------------------------
// ONE preamble launch: all four weight transposes f32 [R,C] -> bf16 [C,R].
// z 0..10 = Wt1 slices, 11..21 = Wt2 slices, 22 = We1, 23 = We2.
// ---------------------------------------------------------------------------
__global__ void transpose_all(const float* __restrict__ Wt1,
                              const float* __restrict__ Wt2,
                              const float* __restrict__ We1,
                              const float* __restrict__ We2,
                              __hip_bfloat16* __restrict__ Wt1t,
                              __hip_bfloat16* __restrict__ Wt2t,
                              __hip_bfloat16* __restrict__ We1t,
                              __hip_bfloat16* __restrict__ We2t) {
  __shared__ float tile[32][33];
  const int z = blockIdx.z;
  int R, C;
  const float* inb;
  __hip_bfloat16* outb;
  if (z < NK) {
    R = ND; C = NH;
    inb = Wt1 + (size_t)z * ND * NH;
    outb = Wt1t + (size_t)z * ND * NH;
  } else if (z < 2 * NK) {
    R = NH; C = ND;
    inb = Wt2 + (size_t)(z - NK) * NH * ND;
    outb = Wt2t + (size_t)(z - NK) * NH * ND;
  } else if (z == 2 * NK) {
    R = ND; C = NH;
    inb = We1; outb = We1t;
  } else {
    R = NH; C = NH;
    inb = We2; outb = We2t;
  }
  int cx = blockIdx.x * 32 + threadIdx.x;
  int ry = blockIdx.y * 32;
  if (blockIdx.x * 32 >= C || ry >= R) return;  // uniform early-out
  for (int j = threadIdx.y; j < 32; j += 8)
    tile[j][threadIdx.x] = inb[(size_t)(ry + j) * C + cx];
  __syncthreads();
  int ox = ry + threadIdx.x;
  int oy = blockIdx.x * 32;
  for (int j = threadIdx.y; j < 32; j += 8)
    outb[(size_t)(oy + j) * R + ox] = __float2bfloat16(tile[threadIdx.x][j]);
}

__device__ __forceinline__ float fast_tanh(float x) {
  float e = __expf(2.0f * x);
  return 1.0f - 2.0f / (e + 1.0f);
}

// ---------------------------------------------------------------------------
// MFMA GEMM (NT): C[M,N] = act(A[M,Kd] * Bt[N,Kd]^T + bias[N])
// R15: FULL REVERT to the proven R11 geometry (all GEMMs 256x128, 512 thr,
// 48 KiB LDS -> 3 blocks/CU; R11 measured 794 us total, MfmaUtil 41.5) —
// both R13 (G4@256x256: 831) and R14 (8-phase port: 939, MfmaUtil 30)
// regressed vs it. R14 post-mortem: 8-phase at 1 blk/CU + lockstep
// barriers + unbalanced 12/4/4/0 ds_read phases reproduced m232's null,
// not m201's 62%. Do NOT re-attempt without the derived-waits schedule.
//
// R15 single lever: MFMA shape 16x16x32 -> 32x32x16. Same LDS bytes/tile
// (16 ds_read_b128/wave), but MFMA-pipe time 155->129 cyc/tile (m06: the
// 32x32 shape runs 2382 vs 2075 TF) and half the MFMA instructions.
// Operand-swapped layouts (A-operand = B-data):
//   frag (both ops): row-in-32-tile = lane&31, k = (lane>>5)*8 + j
//   C/D: M = lane&31, N = (reg&3) + 8*(reg>>2) + 4*(lane>>5)  [m74/m101]
// Wave = 64x64 tile = 2x2 of 32x32, acc 2x2 f32x16 (64 AGPR, same as
// before). Bank pattern of the new b128 reads: uniform 8 accesses/bank
// (conflict-free; SQ_LDS_BANK_CONFLICT must stay 0).
// Grid x = row panel (XCD affinity: FETCH 198->41MB, R4). XOR chunk
// swizzles (conflict-free R5-R11).
// EPI: 1 = tanh->bf16, 2 = relu->bf16, 3 = plain->bf16
// ---------------------------------------------------------------------------
template <int EPI, int BK, int TM, int TN>
__global__ __launch_bounds__((TM / 64) * (TN / 64) * 64) void gemm_bt(
    const __hip_bfloat16* __restrict__ A, long sAz, int lda,
    const __hip_bfloat16* __restrict__ Bt, long sBz, int ldb,
    const float* __restrict__ bias, long sBiasZ,
    __hip_bfloat16* __restrict__ C, long sCz, int ldc, int Kd) {
  static_assert(BK == 64, "R15 path assumes BK=64");
  __shared__ __align__(16) __hip_bfloat16 As[TM * BK];
  __shared__ __align__(16) __hip_bfloat16 Bs[TN * BK];

  const int z = blockIdx.z;
  const __hip_bfloat16* Ab = A + (size_t)z * sAz;
  const __hip_bfloat16* Bb = Bt + (size_t)z * sBz;
  const float* biasb = bias + (size_t)z * sBiasZ;
  __hip_bfloat16* Cb = C + (size_t)z * sCz;

  const int bm = blockIdx.x, bn = blockIdx.y;  // x = row panel (XCD affinity)
  const int t = threadIdx.x;
  constexpr int NWN = TN / 64;
  constexpr int T = (TM / 64) * NWN * 64;  // threads
  const int lane = t & 63, w = t >> 6;
  const int wm = w / NWN, wn = w % NWN;
  const int r32 = lane & 31;  // row within a 32x32 MFMA tile
  const int hi = lane >> 5;   // k-half selector (k = hi*8 + j within K=16)

  f32x16 acc[2][2] = {};

  // Staging chunk->(row, global-offset) with XOR swizzle (self-inverse):
  // LDS slot s of row rw holds global k-chunk (s ^ (rw&7)), 8 bf16/chunk.
  constexpr int CPTA = TM * BK / 8 / T;  // A chunks per thread
  constexpr int CPTB = TN * BK / 8 / T;  // B chunks per thread
  const size_t rowA = (size_t)bm * TM, rowB = (size_t)bn * TN;

  for (int k0 = 0; k0 < Kd; k0 += BK) {
#pragma unroll
    for (int m = 0; m < CPTA; ++m) {
      int c = t + m * T;
      int rw = c >> 3;
      int go = ((c & 7) ^ (rw & 7)) * 8;
      __builtin_amdgcn_global_load_lds(
          (const __attribute__((address_space(1))) void*)(Ab + (rowA + rw) * lda + k0 + go),
          (__attribute__((address_space(3))) void*)(As + c * 8), 16, 0, 0);
    }
#pragma unroll
    for (int m = 0; m < CPTB; ++m) {
      int c = t + m * T;
      int rw = c >> 3;
      int go = ((c & 7) ^ (rw & 7)) * 8;
      __builtin_amdgcn_global_load_lds(
          (const __attribute__((address_space(1))) void*)(Bb + (rowB + rw) * ldb + k0 + go),
          (__attribute__((address_space(3))) void*)(Bs + c * 8), 16, 0, 0);
    }
    __syncthreads();

    // 4 k-slices of 16; per slice: 2 A-frags + 2 B-frags (b128), 4 MFMA.
    // Fragment wants global k-chunk kc = ks*2 + hi -> LDS slot kc ^ (tr&7).
#pragma unroll
    for (int ks = 0; ks < 4; ++ks) {
      bf16x8 af[2], bfr[2];
#pragma unroll
      for (int mt = 0; mt < 2; ++mt) {
        int tr = wm * 64 + mt * 32 + r32;
        int sl = (ks * 2 + hi) ^ (tr & 7);
        af[mt] = *(const bf16x8*)&As[tr * BK + sl * 8];
      }
#pragma unroll
      for (int nt = 0; nt < 2; ++nt) {
        int tr = wn * 64 + nt * 32 + r32;
        int sl = (ks * 2 + hi) ^ (tr & 7);
        bfr[nt] = *(const bf16x8*)&Bs[tr * BK + sl * 8];
      }
#pragma unroll
      for (int mt = 0; mt < 2; ++mt)
#pragma unroll
        for (int nt = 0; nt < 2; ++nt)
          acc[mt][nt] = __builtin_amdgcn_mfma_f32_32x32x16_bf16(
              bfr[nt], af[mt], acc[mt][nt], 0, 0, 0);
    }
    __syncthreads();
  }

  // Epilogue (operand-swapped 32x32 mapping): lane holds M-row =
  // mt*32 + (lane&31); N-cols come in 4 groups g of 4 consecutive:
  // N = nt*32 + g*8 + hi*4 + j  (reg = g*4 + j) -> 8 B packed stores.
  const int colg0 = bn * TN + wn * 64;
  const int rowg0 = bm * TM + wm * 64;
#pragma unroll
  for (int mt = 0; mt < 2; ++mt) {
    int row = rowg0 + mt * 32 + r32;
#pragma unroll
    for (int nt = 0; nt < 2; ++nt) {
#pragma unroll
      for (int g = 0; g < 4; ++g) {
        int col = colg0 + nt * 32 + g * 8 + hi * 4;
        const f32x4 bv = *(const f32x4*)&biasb[col];
        union {
          __hip_bfloat16 h[4];
          uint2 u;
        } pk;
#pragma unroll
        for (int j = 0; j < 4; ++j) {
          float v = acc[mt][nt][g * 4 + j] + bv[j];
          if (EPI == 1) v = fast_tanh(v);
          if (EPI == 2) v = fmaxf(v, 0.0f);
          pk.h[j] = __float2bfloat16(v);
        }
        *(uint2*)&Cb[(size_t)row * ldc + col] = pk.u;
      }
    }
  }
}

// ---------------------------------------------------------------------------
// Final: zc laid [Bc][12][NH]; 2 waves per b (half-H each), partial Grams
// summed in LDS. Block = 256 thr = 2 b's.
// ---------------------------------------------------------------------------
__global__ __launch_bounds__(256) void final_gram(
    const __hip_bfloat16* __restrict__ zc, float* __restrict__ out, int Bc) {
  __shared__ float Gs[2][2][16][16];
  const int t = threadIdx.x;
  const int w = t >> 6, lane = t & 63;
  const int bi = w >> 1;
  const int hh = w & 1;
  const int b = blockIdx.x * 2 + bi;
  const int r = lane & 15;
  const int q = lane >> 4;

  const int rs = r < 12 ? r : 11;
  const __hip_bfloat16* base =
      zc + ((size_t)b * 12 + rs) * NH + hh * (NH / 2) + q * 8;

  f32x4 acc = {};
#pragma unroll
  for (int k0 = 0; k0 < NH / 2; k0 += 32) {
    bf16x8 a = {};
    if (r < 12) a = *(const bf16x8*)(base + k0);
    acc = __builtin_amdgcn_mfma_f32_16x16x32_bf16(a, a, acc, 0, 0, 0);
  }

#pragma unroll
  for (int j = 0; j < 4; ++j) Gs[bi][hh][q * 4 + j][r] = acc[j];
  __syncthreads();

  if (hh == 0) {
    float term = 0.0f;
    if (lane >= 1 && lane < 12) {
      const float(*G0)[16] = Gs[bi][0];
      const float(*G1)[16] = Gs[bi][1];
      float nrm[12];
#pragma unroll
      for (int i = 0; i < 12; ++i)
        nrm[i] = fmaxf(sqrtf(G0[i][i] + G1[i][i]), 1e-8f);
      const int k = lane;
      float pos = __expf((G0[0][k] + G1[0][k]) / (nrm[0] * nrm[k]));
      float neg = 0.0f;
#pragma unroll
      for (int l = 1; l < 12; ++l)
        if (l != k) neg += __expf((G0[k][l] + G1[k][l]) / (nrm[k] * nrm[l]));
      term = __logf(pos / (pos + neg));
    }
#pragma unroll
    for (int m = 1; m < 16; m <<= 1) term += __shfl_xor(term, m);
    if (lane == 0) out[b] = -term;
  }
}

// ---------------------------------------------------------------------------
extern "C" void kernel_launch(void* const* d_in, const int* in_sizes, int n_in,
                              void* d_out, int out_size, void* d_ws,
                              size_t ws_size, hipStream_t stream) {
  const float* x = (const float*)d_in[0];    // [B,D]
  const float* Wt1 = (const float*)d_in[1];  // [K,D,H]
  const float* bt1 = (const float*)d_in[2];  // [K,H]
  const float* Wt2 = (const float*)d_in[3];  // [K,H,D]
  const float* bt2 = (const float*)d_in[4];  // [K,D]
  const float* We1 = (const float*)d_in[5];  // [D,H]
  const float* be1 = (const float*)d_in[6];  // [H]
  const float* We2 = (const float*)d_in[7];  // [H,H]
  const float* be2 = (const float*)d_in[8];  // [H]
  float* out = (float*)d_out;                // [B]

  char* ws = (char*)d_ws;
  size_t off = 0;
  auto alloc = [&](size_t bytes) {
    void* p = ws + off;
    off += (bytes + 255) & ~(size_t)255;
    return p;
  };

  // Persistent bf16 weight transposes (~26 MB)
  __hip_bfloat16* Wt1t = (__hip_bfloat16*)alloc((size_t)NK * NH * ND * 2);  // [K,H,D]
  __hip_bfloat16* Wt2t = (__hip_bfloat16*)alloc((size_t)NK * ND * NH * 2);  // [K,D,H]
  __hip_bfloat16* We1t = (__hip_bfloat16*)alloc((size_t)NH * ND * 2);       // [H,D]
  __hip_bfloat16* We2t = (__hip_bfloat16*)alloc((size_t)NH * NH * 2);       // [H,H]
  const size_t wbytes = off;

  // Pick largest batch chunk Bc (ws in [228,253) MB -> Bc=4096).
  // zc ALIASES txc's region (txc dead after G3).
  int Bc = NB;
  while (Bc > 256) {
    size_t need = wbytes + 2 * ((size_t)12 * Bc * NH * 2) + 4096;
    if (need <= ws_size) break;
    Bc >>= 1;
  }
  __hip_bfloat16* region0 = (__hip_bfloat16*)alloc((size_t)12 * Bc * NH * 2);
  __hip_bfloat16* h1 = (__hip_bfloat16*)alloc((size_t)12 * Bc * NH * 2);
  __hip_bfloat16* txc = region0;  // [12, Bc, ND] during G1..G3
  __hip_bfloat16* zc = region0;   // [Bc, 12, NH] during G4..final

  // One-time: all weight transposes in ONE launch
  transpose_all<<<dim3(NH / 32, NH / 32, 2 * NK + 2), dim3(32, 8), 0,
                  stream>>>(Wt1, Wt2, We1, We2, Wt1t, Wt2t, We1t, We2t);

  for (int cs = 0; cs < NB; cs += Bc) {
    // 1) x chunk -> bf16 (slice 0 of txc)
    cvt_f32_bf16<<<(Bc * ND) / 256, 256, 0, stream>>>(
        x + (size_t)cs * ND, txc, Bc * ND);
    // 2) G1: hx_k = tanh(x @ Wt1[k] + bt1) -> h1 slices 0..10
    gemm_bt<1, 64, 256, 128><<<dim3(Bc / 256, NH / 128, NK), 512, 0,
                               stream>>>(
        txc, 0L, ND, Wt1t, (long)NH * ND, ND, bt1, (long)NH, h1,
        (long)Bc * NH, NH, ND);
    // 3) G2: tx_k = hx_k @ Wt2[k] + bt2 -> txc slices 1..11
    gemm_bt<3, 64, 256, 128><<<dim3(Bc / 256, ND / 128, NK), 512, 0,
                               stream>>>(
        h1, (long)Bc * NH, NH, Wt2t, (long)ND * NH, NH, bt2, (long)ND,
        txc + (size_t)Bc * ND, (long)Bc * ND, ND, NH);
    // 4) G3: e1_s = relu(tx_s @ We1 + be1) -> h1 slices 0..11
    gemm_bt<2, 64, 256, 128><<<dim3(Bc / 256, NH / 128, 12), 512, 0,
                               stream>>>(
        txc, (long)Bc * ND, ND, We1t, 0L, ND, be1, 0L, h1, (long)Bc * NH,
        NH, ND);
    // 5) G4: z_s -> zc [b][s][h] (sCz=NH, ldc=12NH; Kd=1024)
    //    R15: back to 256x128 (R13's 256x256 was 831 vs R11's 794).
    gemm_bt<3, 64, 256, 128><<<dim3(Bc / 256, NH / 128, 12), 512, 0,
                               stream>>>(
        h1, (long)Bc * NH, NH, We2t, 0L, NH, be2, 0L, zc, (long)NH,
        12 * NH, NH);
    // 6) final score
    final_gram<<<Bc / 2, 256, 0, stream>>>(zc, out + cs, Bc);
  }
}

// Round 3
// 735.819 us; speedup vs baseline: 1.2763x; 1.1913x over previous
//
#include <hip/hip_runtime.h>
#include <hip/hip_bf16.h>
#include <cstdint>
#include <cstddef>

// Problem constants (NeuTraLAD): B=8192, D=512, H=1024, K=11 views.
#define NB 8192
#define ND 512
#define NH 1024
#define NK 11

typedef __bf16 bf16x8 __attribute__((ext_vector_type(8)));
typedef float f32x4 __attribute__((ext_vector_type(4)));

// ---------------------------------------------------------------------------
// Convert f32 -> bf16, 8 elems/thread (float4 x2 in, one 16 B store out).
// R16 rider: was scalar (1 elem/thread). n must be a multiple of 8 (Bc*ND is).
// ---------------------------------------------------------------------------
__global__ void cvt_f32_bf16x8(const float* __restrict__ in,
                               __hip_bfloat16* __restrict__ out, int n8) {
  int i = blockIdx.x * blockDim.x + threadIdx.x;
  if (i >= n8) return;
  const float4* p = (const float4*)in + (size_t)i * 2;
  float4 a = p[0], b = p[1];
  union {
    __hip_bfloat16 h[8];
    uint4 u;
  } pk;
  pk.h[0] = __float2bfloat16(a.x);
  pk.h[1] = __float2bfloat16(a.y);
  pk.h[2] = __float2bfloat16(a.z);
  pk.h[3] = __float2bfloat16(a.w);
  pk.h[4] = __float2bfloat16(b.x);
  pk.h[5] = __float2bfloat16(b.y);
  pk.h[6] = __float2bfloat16(b.z);
  pk.h[7] = __float2bfloat16(b.w);
  ((uint4*)out)[i] = pk.u;
}

// ---------------------------------------------------------------------------
// ONE preamble launch: all four weight transposes f32 [R,C] -> bf16 [C,R].
// z 0..10 = Wt1 slices, 11..21 = Wt2 slices, 22 = We1, 23 = We2.
// ---------------------------------------------------------------------------
__global__ void transpose_all(const float* __restrict__ Wt1,
                              const float* __restrict__ Wt2,
                              const float* __restrict__ We1,
                              const float* __restrict__ We2,
                              __hip_bfloat16* __restrict__ Wt1t,
                              __hip_bfloat16* __restrict__ Wt2t,
                              __hip_bfloat16* __restrict__ We1t,
                              __hip_bfloat16* __restrict__ We2t) {
  __shared__ float tile[32][33];
  const int z = blockIdx.z;
  int R, C;
  const float* inb;
  __hip_bfloat16* outb;
  if (z < NK) {
    R = ND; C = NH;
    inb = Wt1 + (size_t)z * ND * NH;
    outb = Wt1t + (size_t)z * ND * NH;
  } else if (z < 2 * NK) {
    R = NH; C = ND;
    inb = Wt2 + (size_t)(z - NK) * NH * ND;
    outb = Wt2t + (size_t)(z - NK) * NH * ND;
  } else if (z == 2 * NK) {
    R = ND; C = NH;
    inb = We1; outb = We1t;
  } else {
    R = NH; C = NH;
    inb = We2; outb = We2t;
  }
  int cx = blockIdx.x * 32 + threadIdx.x;
  int ry = blockIdx.y * 32;
  if (blockIdx.x * 32 >= C || ry >= R) return;  // uniform early-out
  for (int j = threadIdx.y; j < 32; j += 8)
    tile[j][threadIdx.x] = inb[(size_t)(ry + j) * C + cx];
  __syncthreads();
  int ox = ry + threadIdx.x;
  int oy = blockIdx.x * 32;
  for (int j = threadIdx.y; j < 32; j += 8)
    outb[(size_t)(oy + j) * R + ox] = __float2bfloat16(tile[threadIdx.x][j]);
}

__device__ __forceinline__ float fast_tanh(float x) {
  float e = __expf(2.0f * x);
  return 1.0f - 2.0f / (e + 1.0f);
}

// ---------------------------------------------------------------------------
// MFMA GEMM (NT): C[M,N] = act(A[M,Kd] * Bt[N,Kd]^T + bias[N])
// R16: EXACT R11 RESTORATION — the session's proven best (794 us, MfmaUtil
// 41.5). All four GEMMs at 256x128, 512 thr, 16x16x32 MFMA, 48 KiB LDS ->
// 3 blocks/CU (the inter-block overlap IS the latency hiding, m114).
// Experiment ledger (do NOT re-attempt without new evidence):
//   R7: direct-B / single-barrier pipelining — regression.
//   R12: all-256x256 (1024 thr + 64 KB LDS) — crash, cause unisolated.
//   R13: G4-only 256x256 — 831 us (1 blk/CU loses to 3 blk/CU overlap).
//   R14: m201-style 8-phase port (128 KB LDS, counted vmcnt(6), setprio)
//        — 939 us, MfmaUtil 30: reproduced m232's null quadrant, not
//        m201's 62%. Also FETCH/WRITE inflated 1.35-1.5x (unexplained).
//   R15: MFMA 32x32x16 swap — 876 us, SQ_LDS_BANK_CONFLICT 0 -> 1.26e7
//        despite per-instruction bank analysis predicting parity; MFMA
//        busy-cycles rose. Reverted.
// TM x TN block tile, (TM/64)*(TN/64) waves, wave = 64x64 sub-tile via 4x4
// mfma_f32_16x16x32_bf16. Grid x = row panel (XCD affinity: FETCH
// 198->41MB, R4). XOR chunk swizzles (conflict-free R5-R11). MFMA operands
// swapped -> lane holds 4 consecutive cols of C -> 8 B packed stores.
// EPI: 1 = tanh->bf16, 2 = relu->bf16, 3 = plain->bf16
// ---------------------------------------------------------------------------
template <int EPI, int BK, int TM, int TN>
__global__ __launch_bounds__((TM / 64) * (TN / 64) * 64) void gemm_bt(
    const __hip_bfloat16* __restrict__ A, long sAz, int lda,
    const __hip_bfloat16* __restrict__ Bt, long sBz, int ldb,
    const float* __restrict__ bias, long sBiasZ,
    __hip_bfloat16* __restrict__ C, long sCz, int ldc, int Kd) {
  __shared__ __align__(16) __hip_bfloat16 As[TM * BK];
  __shared__ __align__(16) __hip_bfloat16 Bs[TN * BK];

  const int z = blockIdx.z;
  const __hip_bfloat16* Ab = A + (size_t)z * sAz;
  const __hip_bfloat16* Bb = Bt + (size_t)z * sBz;
  const float* biasb = bias + (size_t)z * sBiasZ;
  __hip_bfloat16* Cb = C + (size_t)z * sCz;

  const int bm = blockIdx.x, bn = blockIdx.y;  // x = row panel (XCD affinity)
  const int t = threadIdx.x;
  constexpr int NWN = TN / 64;
  constexpr int T = (TM / 64) * NWN * 64;  // threads
  const int lane = t & 63, w = t >> 6;
  const int wm = w / NWN, wn = w % NWN;
  const int r = lane & 15, q = lane >> 4;

  f32x4 acc[4][4] = {};

  // Staging chunk->(row, global-offset) with XOR swizzle (self-inverse).
  auto chunk_row = [&](int c) {
    return (BK == 32) ? (c >> 2) : (c >> 3);
  };
  auto chunk_gofs = [&](int c, int row) {
    return (BK == 32) ? ((((c & 3) ^ ((row >> 1) & 3)) * 8))
                      : ((((c & 7) ^ (row & 7)) * 8));
  };
  constexpr int CPTA = TM * BK / 8 / T;  // A chunks per thread
  constexpr int CPTB = TN * BK / 8 / T;  // B chunks per thread
  const size_t rowA = (size_t)bm * TM, rowB = (size_t)bn * TN;

  for (int k0 = 0; k0 < Kd; k0 += BK) {
#pragma unroll
    for (int m = 0; m < CPTA; ++m) {
      int c = t + m * T;
      int rw = chunk_row(c);
      __builtin_amdgcn_global_load_lds(
          (const __attribute__((address_space(1))) void*)(Ab + (rowA + rw) * lda + k0 + chunk_gofs(c, rw)),
          (__attribute__((address_space(3))) void*)(As + c * 8), 16, 0, 0);
    }
#pragma unroll
    for (int m = 0; m < CPTB; ++m) {
      int c = t + m * T;
      int rw = chunk_row(c);
      __builtin_amdgcn_global_load_lds(
          (const __attribute__((address_space(1))) void*)(Bb + (rowB + rw) * ldb + k0 + chunk_gofs(c, rw)),
          (__attribute__((address_space(3))) void*)(Bs + c * 8), 16, 0, 0);
    }
    __syncthreads();

#pragma unroll
    for (int ks = 0; ks < BK / 32; ++ks) {
      bf16x8 af[4], bfr[4];
#pragma unroll
      for (int mt = 0; mt < 4; ++mt) {
        int tr = wm * 64 + mt * 16 + r;
        int sl;
        if constexpr (BK == 32) sl = q ^ ((tr >> 1) & 3);
        else sl = (ks * 4 + q) ^ (tr & 7);
        af[mt] = *(const bf16x8*)&As[tr * BK + sl * 8];
      }
#pragma unroll
      for (int nt = 0; nt < 4; ++nt) {
        int tr = wn * 64 + nt * 16 + r;
        int sl;
        if constexpr (BK == 32) sl = q ^ ((tr >> 1) & 3);
        else sl = (ks * 4 + q) ^ (tr & 7);
        bfr[nt] = *(const bf16x8*)&Bs[tr * BK + sl * 8];
      }
#pragma unroll
      for (int mt = 0; mt < 4; ++mt)
#pragma unroll
        for (int nt = 0; nt < 4; ++nt)
          acc[mt][nt] = __builtin_amdgcn_mfma_f32_16x16x32_bf16(
              bfr[nt], af[mt], acc[mt][nt], 0, 0, 0);
    }
    __syncthreads();
  }

  // Epilogue (operand-swapped): lane holds M-row = mt*16 + r, N-cols =
  // nt*16 + q*4 + j (consecutive) -> 8 B packed stores.
  const int colg0 = bn * TN + wn * 64;
  const int rowg0 = bm * TM + wm * 64;
#pragma unroll
  for (int mt = 0; mt < 4; ++mt) {
    int row = rowg0 + mt * 16 + r;
#pragma unroll
    for (int nt = 0; nt < 4; ++nt) {
      int col = colg0 + nt * 16 + q * 4;
      const f32x4 bv = *(const f32x4*)&biasb[col];
      union {
        __hip_bfloat16 h[4];
        uint2 u;
      } pk;
#pragma unroll
      for (int j = 0; j < 4; ++j) {
        float v = acc[mt][nt][j] + bv[j];
        if (EPI == 1) v = fast_tanh(v);
        if (EPI == 2) v = fmaxf(v, 0.0f);
        pk.h[j] = __float2bfloat16(v);
      }
      *(uint2*)&Cb[(size_t)row * ldc + col] = pk.u;
    }
  }
}

// ---------------------------------------------------------------------------
// Final: zc laid [Bc][12][NH]; 2 waves per b (half-H each), partial Grams
// summed in LDS. Block = 256 thr = 2 b's.
// ---------------------------------------------------------------------------
__global__ __launch_bounds__(256) void final_gram(
    const __hip_bfloat16* __restrict__ zc, float* __restrict__ out, int Bc) {
  __shared__ float Gs[2][2][16][16];
  const int t = threadIdx.x;
  const int w = t >> 6, lane = t & 63;
  const int bi = w >> 1;
  const int hh = w & 1;
  const int b = blockIdx.x * 2 + bi;
  const int r = lane & 15;
  const int q = lane >> 4;

  const int rs = r < 12 ? r : 11;
  const __hip_bfloat16* base =
      zc + ((size_t)b * 12 + rs) * NH + hh * (NH / 2) + q * 8;

  f32x4 acc = {};
#pragma unroll
  for (int k0 = 0; k0 < NH / 2; k0 += 32) {
    bf16x8 a = {};
    if (r < 12) a = *(const bf16x8*)(base + k0);
    acc = __builtin_amdgcn_mfma_f32_16x16x32_bf16(a, a, acc, 0, 0, 0);
  }

#pragma unroll
  for (int j = 0; j < 4; ++j) Gs[bi][hh][q * 4 + j][r] = acc[j];
  __syncthreads();

  if (hh == 0) {
    float term = 0.0f;
    if (lane >= 1 && lane < 12) {
      const float(*G0)[16] = Gs[bi][0];
      const float(*G1)[16] = Gs[bi][1];
      float nrm[12];
#pragma unroll
      for (int i = 0; i < 12; ++i)
        nrm[i] = fmaxf(sqrtf(G0[i][i] + G1[i][i]), 1e-8f);
      const int k = lane;
      float pos = __expf((G0[0][k] + G1[0][k]) / (nrm[0] * nrm[k]));
      float neg = 0.0f;
#pragma unroll
      for (int l = 1; l < 12; ++l)
        if (l != k) neg += __expf((G0[k][l] + G1[k][l]) / (nrm[k] * nrm[l]));
      term = __logf(pos / (pos + neg));
    }
#pragma unroll
    for (int m = 1; m < 16; m <<= 1) term += __shfl_xor(term, m);
    if (lane == 0) out[b] = -term;
  }
}

// ---------------------------------------------------------------------------
extern "C" void kernel_launch(void* const* d_in, const int* in_sizes, int n_in,
                              void* d_out, int out_size, void* d_ws,
                              size_t ws_size, hipStream_t stream) {
  const float* x = (const float*)d_in[0];    // [B,D]
  const float* Wt1 = (const float*)d_in[1];  // [K,D,H]
  const float* bt1 = (const float*)d_in[2];  // [K,H]
  const float* Wt2 = (const float*)d_in[3];  // [K,H,D]
  const float* bt2 = (const float*)d_in[4];  // [K,D]
  const float* We1 = (const float*)d_in[5];  // [D,H]
  const float* be1 = (const float*)d_in[6];  // [H]
  const float* We2 = (const float*)d_in[7];  // [H,H]
  const float* be2 = (const float*)d_in[8];  // [H]
  float* out = (float*)d_out;                // [B]

  char* ws = (char*)d_ws;
  size_t off = 0;
  auto alloc = [&](size_t bytes) {
    void* p = ws + off;
    off += (bytes + 255) & ~(size_t)255;
    return p;
  };

  // Persistent bf16 weight transposes (~26 MB)
  __hip_bfloat16* Wt1t = (__hip_bfloat16*)alloc((size_t)NK * NH * ND * 2);  // [K,H,D]
  __hip_bfloat16* Wt2t = (__hip_bfloat16*)alloc((size_t)NK * ND * NH * 2);  // [K,D,H]
  __hip_bfloat16* We1t = (__hip_bfloat16*)alloc((size_t)NH * ND * 2);       // [H,D]
  __hip_bfloat16* We2t = (__hip_bfloat16*)alloc((size_t)NH * NH * 2);       // [H,H]
  const size_t wbytes = off;

  // Pick largest batch chunk Bc (ws in [228,253) MB -> Bc=4096).
  // zc ALIASES txc's region (txc dead after G3).
  int Bc = NB;
  while (Bc > 256) {
    size_t need = wbytes + 2 * ((size_t)12 * Bc * NH * 2) + 4096;
    if (need <= ws_size) break;
    Bc >>= 1;
  }
  __hip_bfloat16* region0 = (__hip_bfloat16*)alloc((size_t)12 * Bc * NH * 2);
  __hip_bfloat16* h1 = (__hip_bfloat16*)alloc((size_t)12 * Bc * NH * 2);
  __hip_bfloat16* txc = region0;  // [12, Bc, ND] during G1..G3
  __hip_bfloat16* zc = region0;   // [Bc, 12, NH] during G4..final

  // One-time: all weight transposes in ONE launch
  transpose_all<<<dim3(NH / 32, NH / 32, 2 * NK + 2), dim3(32, 8), 0,
                  stream>>>(Wt1, Wt2, We1, We2, Wt1t, Wt2t, We1t, We2t);

  for (int cs = 0; cs < NB; cs += Bc) {
    // 1) x chunk -> bf16 (slice 0 of txc), 8 elems/thread
    cvt_f32_bf16x8<<<(Bc * ND / 8) / 256, 256, 0, stream>>>(
        x + (size_t)cs * ND, txc, Bc * ND / 8);
    // 2) G1: hx_k = tanh(x @ Wt1[k] + bt1) -> h1 slices 0..10
    gemm_bt<1, 64, 256, 128><<<dim3(Bc / 256, NH / 128, NK), 512, 0,
                               stream>>>(
        txc, 0L, ND, Wt1t, (long)NH * ND, ND, bt1, (long)NH, h1,
        (long)Bc * NH, NH, ND);
    // 3) G2: tx_k = hx_k @ Wt2[k] + bt2 -> txc slices 1..11
    gemm_bt<3, 64, 256, 128><<<dim3(Bc / 256, ND / 128, NK), 512, 0,
                               stream>>>(
        h1, (long)Bc * NH, NH, Wt2t, (long)ND * NH, NH, bt2, (long)ND,
        txc + (size_t)Bc * ND, (long)Bc * ND, ND, NH);
    // 4) G3: e1_s = relu(tx_s @ We1 + be1) -> h1 slices 0..11
    gemm_bt<2, 64, 256, 128><<<dim3(Bc / 256, NH / 128, 12), 512, 0,
                               stream>>>(
        txc, (long)Bc * ND, ND, We1t, 0L, ND, be1, 0L, h1, (long)Bc * NH,
        NH, ND);
    // 5) G4: z_s -> zc [b][s][h] (sCz=NH, ldc=12NH; Kd=1024) — R11 config
    gemm_bt<3, 64, 256, 128><<<dim3(Bc / 256, NH / 128, 12), 512, 0,
                               stream>>>(
        h1, (long)Bc * NH, NH, We2t, 0L, NH, be2, 0L, zc, (long)NH,
        12 * NH, NH);
    // 6) final score
    final_gram<<<Bc / 2, 256, 0, stream>>>(zc, out + cs, Bc);
  }
}